// Round 5
// baseline (1833.278 us; speedup 1.0000x reference)
//
#include <hip/hip_runtime.h>

#define NEG_SLOPE 0.01f

typedef __attribute__((ext_vector_type(8))) short short8;
typedef __attribute__((ext_vector_type(4))) float f32x4;
typedef unsigned short u16;
typedef unsigned int u32;

__device__ __forceinline__ u16 f2bf(float f) {
  u32 u = __float_as_uint(f);
  u32 r = (u + 0x7FFFu + ((u >> 16) & 1u)) >> 16;  // RNE
  return (u16)r;
}
__device__ __forceinline__ float bf2f(u16 h) { return __uint_as_float(((u32)h) << 16); }

__device__ __forceinline__ void gl_lds16(const void* g, void* l) {
  __builtin_amdgcn_global_load_lds((const __attribute__((address_space(1))) u32*)g,
                                   (__attribute__((address_space(3))) u32*)l, 16, 0, 0);
}

// ---------------- conversion kernels ----------------

// x [M][128] f32 -> chunked bf16 [4][M][32]
__global__ __launch_bounds__(256) void cvt_x_kernel(const float* __restrict__ x,
                                                    u16* __restrict__ xbf, int M) {
  size_t i4 = ((size_t)blockIdx.x * blockDim.x + threadIdx.x) * 4;
  size_t total = (size_t)4 * M * 32;
  if (i4 >= total) return;
  int k2 = (int)(i4 & 31);
  size_t t = i4 >> 5;
  int row = (int)(t % (size_t)M);
  int kc  = (int)(t / (size_t)M);
  float4 v = *(const float4*)(x + (size_t)row * 128 + kc * 32 + k2);
  ushort4 o;
  o.x = f2bf(v.x); o.y = f2bf(v.y); o.z = f2bf(v.z); o.w = f2bf(v.w);
  *(ushort4*)(xbf + i4) = o;
}

// W [Kin][Kout] f32 -> chunked bf16 [Kin/32][Kout][32] (W^T k-granules)
__global__ __launch_bounds__(256) void cvt_w_kernel(const float* __restrict__ W,
                                                    u16* __restrict__ dst, int Kout, size_t n) {
  size_t i4 = ((size_t)blockIdx.x * blockDim.x + threadIdx.x) * 4;
  if (i4 >= n) return;
  int k2 = (int)(i4 & 31);
  size_t t = i4 >> 5;
  int col = (int)(t % (size_t)Kout);
  int kc  = (int)(t / (size_t)Kout);
  ushort4 o;
  o.x = f2bf(W[(size_t)(kc * 32 + k2 + 0) * Kout + col]);
  o.y = f2bf(W[(size_t)(kc * 32 + k2 + 1) * Kout + col]);
  o.z = f2bf(W[(size_t)(kc * 32 + k2 + 2) * Kout + col]);
  o.w = f2bf(W[(size_t)(kc * 32 + k2 + 3) * Kout + col]);
  *(ushort4*)(dst + i4) = o;
}

// ---------------- main GEMM pass (m97 structure + T1 bijective XCD swizzle) ----------------
// C[mc][N] = act(A_chunk[mc][K] @ W[K][N] + bias (+ sigma_h gather))
// A chunked [K/32][Astride][32] bf16 (base pre-offset to this row-chunk);
// W chunked [K/32][N][32] bf16.
// OUTMODE: 0 = chunked bf16 (stride OutStride), 1 = row-major bf16 (local rows),
//          2 = row-major f32 (outp pre-offset to chunk).
// batch pre-offset to chunk; indices masked &63 (G=64) so bad data can't fault.
template <bool LEAKY, int OUTMODE, bool GATHER, int CB>
__global__ __launch_bounds__(256) void gemm_pass(
    const u16* __restrict__ A, int Astride, const u16* __restrict__ W,
    const float* __restrict__ bias, void* __restrict__ outp, int OutStride,
    const int* __restrict__ batch, const float* __restrict__ sigma_h,
    int mc, int N, int K) {
  __shared__ u16 Atile[2][128 * 32];
  __shared__ u16 Btile[2][128 * 32];
  const int tid = threadIdx.x;
  const int wave = tid >> 6;
  const int lane = tid & 63;
  const int wr = wave >> 1, wc = wave & 1;
  const int l15 = lane & 15, q = lane >> 4;

  // m204 bijective XCD-chunked swizzle (valid for any nwg)
  const int nwg = gridDim.x;
  const int bid = blockIdx.x;
  const int qq = nwg >> 3, rr = nwg & 7;
  const int xcd = bid & 7;
  const int base = xcd < rr ? xcd * (qq + 1) : rr * (qq + 1) + (xcd - rr) * qq;
  const int w = base + (bid >> 3);
  const int rowg = w / CB;          // CB compile-time: shift
  const int colg = w - rowg * CB;
  const int row0 = rowg * 128;
  const int col0 = colg * 128;
  const int NK = K >> 5;

  // stage one 8KB tile (512 x 16B granules); LDS dest wave-uniform + lane*16 (linear both sides)
  auto stage = [&](const u16* basep, size_t granule0, u16* tile) {
    const char* src = (const char*)basep + granule0 * 16;
    char* wbase = (char*)tile + (size_t)wave * 1024;
    gl_lds16(src + (size_t)tid * 16, wbase);
    gl_lds16(src + (size_t)(tid + 256) * 16, wbase + 4096);
  };

  stage(A, ((size_t)0 * Astride + row0) * 4, &Atile[0][0]);
  stage(W, ((size_t)0 * N + col0) * 4, &Btile[0][0]);

  f32x4 acc[4][4];
#pragma unroll
  for (int n = 0; n < 4; ++n) {
    float bv = bias[col0 + wc * 64 + n * 16 + l15];
    f32x4 init = {bv, bv, bv, bv};
#pragma unroll
    for (int m = 0; m < 4; ++m) acc[m][n] = init;
  }

  int cur = 0;
  for (int kc = 0; kc < NK; ++kc) {
    __syncthreads();  // vmcnt(0)+lgkmcnt(0) drained before s_barrier (compiler-emitted)
    if (kc + 1 < NK) {
      stage(A, ((size_t)(kc + 1) * Astride + row0) * 4, &Atile[cur ^ 1][0]);
      stage(W, ((size_t)(kc + 1) * N + col0) * 4, &Btile[cur ^ 1][0]);
    }
    short8 a[4], b[4];
#pragma unroll
    for (int m = 0; m < 4; ++m)
      a[m] = *(const short8*)&Atile[cur][(wr * 64 + m * 16 + l15) * 32 + q * 8];
#pragma unroll
    for (int n = 0; n < 4; ++n)
      b[n] = *(const short8*)&Btile[cur][(wc * 64 + n * 16 + l15) * 32 + q * 8];
#pragma unroll
    for (int m = 0; m < 4; ++m)
#pragma unroll
      for (int n = 0; n < 4; ++n)
        acc[m][n] = __builtin_amdgcn_mfma_f32_16x16x32_bf16(a[m], b[n], acc[m][n], 0, 0, 0);
    cur ^= 1;
  }

  // epilogue: D row = (lane>>4)*4 + reg, col = lane&15 (m89-verified map)
#pragma unroll
  for (int m = 0; m < 4; ++m) {
#pragma unroll
    for (int r = 0; r < 4; ++r) {
      int row = row0 + wr * 64 + m * 16 + q * 4 + r;
      if (row >= mc) continue;
      int gidx = 0;
      if (GATHER) gidx = batch[row] & 63;  // mask: bad batch data -> wrong result, not fault
#pragma unroll
      for (int n = 0; n < 4; ++n) {
        int col = col0 + wc * 64 + n * 16 + l15;
        float v = acc[m][n][r];
        if (GATHER) v += sigma_h[(size_t)gidx * 512 + col];
        if (LEAKY) v = v >= 0.f ? v : NEG_SLOPE * v;
        if (OUTMODE == 0)
          ((u16*)outp)[((size_t)(col >> 5) * OutStride + row) * 32 + (col & 31)] = f2bf(v);
        else if (OUTMODE == 1)
          ((u16*)outp)[(size_t)row * N + col] = f2bf(v);
        else
          ((float*)outp)[(size_t)row * N + col] = v;
      }
    }
  }
}

// ---------------- segment sum (batch sorted; local rows, batch pre-offset) ----------------
#define SS_ROWS 512
__global__ __launch_bounds__(1024) void segsum_kernel(const u16* __restrict__ emb,
                                                      const int* __restrict__ batch,
                                                      float* __restrict__ seg,
                                                      float* __restrict__ cnt, int mc) {
  __shared__ int bsh[SS_ROWS];
  int r0 = blockIdx.x * SS_ROWS;
  int tid = threadIdx.x;          // 1024
  int c = tid & 255, sub = tid >> 8;
  int nrows = mc - r0;
  if (nrows > SS_ROWS) nrows = SS_ROWS;
  for (int i = tid; i < nrows; i += 1024) bsh[i] = batch[r0 + i] & 63;  // masked
  __syncthreads();
  int i0 = sub * 128, i1 = i0 + 128;
  if (i1 > nrows) i1 = nrows;
  if (i0 < nrows) {
    float acc = 0.f;
    int curg = bsh[i0];
    for (int i = i0; i < i1; ++i) {
      int b = bsh[i];
      if (b != curg) { atomicAdd(&seg[(size_t)curg * 256 + c], acc); acc = 0.f; curg = b; }
      acc += bf2f(emb[(size_t)(r0 + i) * 256 + c]);
    }
    atomicAdd(&seg[(size_t)curg * 256 + c], acc);
    if (c == 0) {
      float ca = 0.f;
      int cu = bsh[i0];
      for (int i = i0; i < i1; ++i) {
        int b = bsh[i];
        if (b != cu) { atomicAdd(&cnt[cu], ca); ca = 0.f; cu = b; }
        ca += 1.f;
      }
      atomicAdd(&cnt[cu], ca);
    }
  }
}

// ---------------- sigma / sigma_h (fp32, tiny: G=64) ----------------
__global__ __launch_bounds__(512) void sigma_kernel(const float* __restrict__ seg,
                                                    const float* __restrict__ cnt,
                                                    const float* __restrict__ w_ag,
                                                    const float* __restrict__ b_ag,
                                                    float* __restrict__ sigma_h) {
  __shared__ float s[256];
  int g = blockIdx.x, t = threadIdx.x;  // 512 threads
  if (t < 256) {
    float c = fmaxf(cnt[g], 1.0f);
    s[t] = seg[(size_t)g * 256 + t] / c;
  }
  __syncthreads();
  float acc = b_ag[t];
  for (int k = 0; k < 256; ++k) acc += s[k] * w_ag[(size_t)k * 512 + t];
  sigma_h[(size_t)g * 512 + t] = acc;
}

// ---------------- host ----------------
extern "C" void kernel_launch(void* const* d_in, const int* in_sizes, int n_in,
                              void* d_out, int out_size, void* d_ws, size_t ws_size,
                              hipStream_t stream) {
  const float* x = (const float*)d_in[0];
  const int* batch = (const int*)d_in[1];  // harness contract: integer -> const int*
  const int M = in_sizes[0] / 128;  // 200000
  const float* phi_b[4] = {(const float*)d_in[4], (const float*)d_in[6],
                           (const float*)d_in[8], (const float*)d_in[10]};
  const float* psi_b[4] = {(const float*)d_in[12], (const float*)d_in[14],
                           (const float*)d_in[16], (const float*)d_in[18]};
  const float* b_in = (const float*)d_in[20];
  const float* w_ag = (const float*)d_in[21];
  const float* b_ag = (const float*)d_in[22];

  // weight pack order: phi0..phi3, w_in, psi0..psi3
  const int wkin[9]  = {128, 512, 512, 512, 128, 512, 512, 512, 512};
  const int wkout[9] = {512, 512, 512, 256, 512, 512, 512, 512, 128};
  const float* wsrc[9] = {(const float*)d_in[3], (const float*)d_in[5], (const float*)d_in[7],
                          (const float*)d_in[9], (const float*)d_in[19], (const float*)d_in[11],
                          (const float*)d_in[13], (const float*)d_in[15], (const float*)d_in[17]};

  // ---- adaptive row-chunking so workspace fits ws_size (floor P=4) ----
  size_t wbytes = 0;
  for (int i = 0; i < 9; ++i)
    wbytes += (((size_t)wkin[i] * wkout[i] * 2) + 255) & ~(size_t)255;
  const size_t xbf_b  = (((size_t)4 * M * 32 * 2 + 16384) + 255) & ~(size_t)255;
  const size_t tail_b = 65536 + 256 + 256 + 131072 + 1024;  // seg+cnt+sigh+align slop
  size_t wsz = ws_size ? ws_size : (size_t)1 << 40;
  int McCap = 0;
  for (int P = 4; ; P *= 2) {
    int mcc = ((M + P - 1) / P + 127) / 128 * 128;
    size_t buf_b = (((size_t)16 * mcc * 32 * 2 + 16384) + 255) & ~(size_t)255;
    if (wbytes + xbf_b + 2 * buf_b + tail_b <= wsz || P >= 64) { McCap = mcc; break; }
  }

  char* ws = (char*)d_ws;
  size_t o = 0;
  auto alloc = [&](size_t bytes) {
    size_t r = o;
    o = (o + bytes + 255) & ~(size_t)255;
    return r;
  };
  u16* wdst[9];
  for (int i = 0; i < 9; ++i) wdst[i] = (u16*)(ws + alloc((size_t)wkin[i] * wkout[i] * 2));
  u16* xbf = (u16*)(ws + alloc((size_t)4 * M * 32 * 2 + 16384));
  u16* bufA = (u16*)(ws + alloc((size_t)16 * McCap * 32 * 2 + 16384));
  u16* bufB = (u16*)(ws + alloc((size_t)16 * McCap * 32 * 2 + 16384));
  float* seg = (float*)(ws + alloc((size_t)64 * 256 * 4));
  float* cnt = (float*)(ws + alloc(64 * 4));
  float* sigh = (float*)(ws + alloc((size_t)64 * 512 * 4));
  (void)n_in; (void)out_size;

  // pack weights + x to bf16 chunked layouts
  for (int i = 0; i < 9; ++i) {
    size_t n = (size_t)wkin[i] * wkout[i];
    int blocks = (int)((n / 4 + 255) / 256);
    hipLaunchKernelGGL(cvt_w_kernel, dim3(blocks), dim3(256), 0, stream, wsrc[i], wdst[i],
                       wkout[i], n);
  }
  {
    size_t total = (size_t)4 * M * 32;
    int blocks = (int)((total / 4 + 255) / 256);
    hipLaunchKernelGGL(cvt_x_kernel, dim3(blocks), dim3(256), 0, stream, x, xbf, M);
  }

  const int* nob = nullptr;
  const float* nof = nullptr;
  const int nChunks = (M + McCap - 1) / McCap;

  // phi chain + segment-sum, per row-chunk (seg accumulates across chunks)
  hipMemsetAsync(seg, 0, (size_t)64 * 256 * 4 + 256, stream);  // seg + cnt contiguous
  for (int c = 0; c < nChunks; ++c) {
    const int cs = c * McCap;
    const int mc = (M - cs < McCap) ? (M - cs) : McCap;
    if (mc <= 0) break;
    const int RBc = (mc + 127) / 128;
    const u16* xc = xbf + (size_t)cs * 32;
    gemm_pass<true, 0, false, 4><<<RBc * 4, 256, 0, stream>>>(xc, M, wdst[0], phi_b[0], bufA, McCap, nob, nof, mc, 512, 128);
    gemm_pass<true, 0, false, 4><<<RBc * 4, 256, 0, stream>>>(bufA, McCap, wdst[1], phi_b[1], bufB, McCap, nob, nof, mc, 512, 512);
    gemm_pass<true, 0, false, 4><<<RBc * 4, 256, 0, stream>>>(bufB, McCap, wdst[2], phi_b[2], bufA, McCap, nob, nof, mc, 512, 512);
    gemm_pass<true, 1, false, 2><<<RBc * 2, 256, 0, stream>>>(bufA, McCap, wdst[3], phi_b[3], bufB, 0, nob, nof, mc, 256, 512);
    hipLaunchKernelGGL(segsum_kernel, dim3((mc + SS_ROWS - 1) / SS_ROWS), dim3(1024), 0, stream,
                       bufB, batch + cs, seg, cnt, mc);
  }

  hipLaunchKernelGGL(sigma_kernel, dim3(64), dim3(512), 0, stream, seg, cnt, w_ag, b_ag, sigh);

  // psi chain per row-chunk: psi_in = leaky(x@w_in + b_in + sigma_h[batch]); last layer f32->d_out
  for (int c = 0; c < nChunks; ++c) {
    const int cs = c * McCap;
    const int mc = (M - cs < McCap) ? (M - cs) : McCap;
    if (mc <= 0) break;
    const int RBc = (mc + 127) / 128;
    const u16* xc = xbf + (size_t)cs * 32;
    float* outc = (float*)d_out + (size_t)cs * 128;
    gemm_pass<true, 0, true, 4><<<RBc * 4, 256, 0, stream>>>(xc, M, wdst[4], b_in, bufA, McCap, batch + cs, sigh, mc, 512, 128);
    gemm_pass<true, 0, false, 4><<<RBc * 4, 256, 0, stream>>>(bufA, McCap, wdst[5], psi_b[0], bufB, McCap, nob, nof, mc, 512, 512);
    gemm_pass<true, 0, false, 4><<<RBc * 4, 256, 0, stream>>>(bufB, McCap, wdst[6], psi_b[1], bufA, McCap, nob, nof, mc, 512, 512);
    gemm_pass<true, 0, false, 4><<<RBc * 4, 256, 0, stream>>>(bufA, McCap, wdst[7], psi_b[2], bufB, McCap, nob, nof, mc, 512, 512);
    gemm_pass<false, 2, false, 1><<<RBc * 1, 256, 0, stream>>>(bufB, McCap, wdst[8], psi_b[3], outc, 0, nob, nof, mc, 128, 512);
  }
}

// Round 8
// 1503.132 us; speedup vs baseline: 1.2196x; 1.2196x over previous
//
#include <hip/hip_runtime.h>

#define NEG_SLOPE 0.01f

typedef __attribute__((ext_vector_type(8))) short short8;
typedef __attribute__((ext_vector_type(4))) float f32x4;
typedef unsigned short u16;
typedef unsigned int u32;

__device__ __forceinline__ u16 f2bf(float f) {
  u32 u = __float_as_uint(f);
  u32 r = (u + 0x7FFFu + ((u >> 16) & 1u)) >> 16;  // RNE
  return (u16)r;
}
__device__ __forceinline__ float bf2f(u16 h) { return __uint_as_float(((u32)h) << 16); }

__device__ __forceinline__ void gl_lds16(const void* g, void* l) {
  __builtin_amdgcn_global_load_lds((const __attribute__((address_space(1))) u32*)g,
                                   (__attribute__((address_space(3))) u32*)l, 16, 0, 0);
}

// ---------------- conversion kernels ----------------

// x [M][128] f32 -> chunked bf16 [4][M][32]
__global__ __launch_bounds__(256) void cvt_x_kernel(const float* __restrict__ x,
                                                    u16* __restrict__ xbf, int M) {
  size_t i4 = ((size_t)blockIdx.x * blockDim.x + threadIdx.x) * 4;
  size_t total = (size_t)4 * M * 32;
  if (i4 >= total) return;
  int k2 = (int)(i4 & 31);
  size_t t = i4 >> 5;
  int row = (int)(t % (size_t)M);
  int kc  = (int)(t / (size_t)M);
  float4 v = *(const float4*)(x + (size_t)row * 128 + kc * 32 + k2);
  ushort4 o;
  o.x = f2bf(v.x); o.y = f2bf(v.y); o.z = f2bf(v.z); o.w = f2bf(v.w);
  *(ushort4*)(xbf + i4) = o;
}

// All 9 weights W [Kin][Kout] f32 -> chunked bf16 [Kin/32][Kout][32], one launch.
struct WPack {
  const float* src[9];
  u16* dst[9];
  int kout[9];
  int n4[9];  // (Kin*Kout)/4 granule count
};
__global__ __launch_bounds__(256) void cvt_w_all_kernel(WPack p) {
  int wi = blockIdx.y;
  int idx = blockIdx.x * 256 + threadIdx.x;
  if (idx >= p.n4[wi]) return;
  const float* W = p.src[wi];
  int Kout = p.kout[wi];
  size_t i4 = (size_t)idx * 4;
  int k2 = (int)(i4 & 31);
  size_t t = i4 >> 5;
  int col = (int)(t % (size_t)Kout);
  int kc  = (int)(t / (size_t)Kout);
  ushort4 o;
  o.x = f2bf(W[(size_t)(kc * 32 + k2 + 0) * Kout + col]);
  o.y = f2bf(W[(size_t)(kc * 32 + k2 + 1) * Kout + col]);
  o.z = f2bf(W[(size_t)(kc * 32 + k2 + 2) * Kout + col]);
  o.w = f2bf(W[(size_t)(kc * 32 + k2 + 3) * Kout + col]);
  *(ushort4*)(p.dst[wi] + i4) = o;
}

// ---------------- main GEMM pass (m97 structure + T1 bijective XCD swizzle) ----------------
// C[mc][N] = act(A_chunk[mc][K] @ W[K][N] + bias (+ sigma_h gather))
// A chunked [K/32][Astride][32] bf16 (base pre-offset to this row-chunk);
// W chunked [K/32][N][32] bf16.
// OUTMODE: 0 = chunked bf16 (stride OutStride), 1 = row-major bf16 (local rows),
//          2 = row-major f32 (outp pre-offset to chunk).
template <bool LEAKY, int OUTMODE, bool GATHER, int CB>
__global__ __launch_bounds__(256) void gemm_pass(
    const u16* __restrict__ A, int Astride, const u16* __restrict__ W,
    const float* __restrict__ bias, void* __restrict__ outp, int OutStride,
    const int* __restrict__ batch, const float* __restrict__ sigma_h,
    int mc, int N, int K) {
  __shared__ u16 Atile[2][128 * 32];
  __shared__ u16 Btile[2][128 * 32];
  const int tid = threadIdx.x;
  const int wave = tid >> 6;
  const int lane = tid & 63;
  const int wr = wave >> 1, wc = wave & 1;
  const int l15 = lane & 15, q = lane >> 4;

  // m204 bijective XCD-chunked swizzle (valid for any nwg)
  const int nwg = gridDim.x;
  const int bid = blockIdx.x;
  const int qq = nwg >> 3, rr = nwg & 7;
  const int xcd = bid & 7;
  const int base = xcd < rr ? xcd * (qq + 1) : rr * (qq + 1) + (xcd - rr) * qq;
  const int w = base + (bid >> 3);
  const int rowg = w / CB;          // CB compile-time: shift
  const int colg = w - rowg * CB;
  const int row0 = rowg * 128;
  const int col0 = colg * 128;
  const int NK = K >> 5;

  // stage one 8KB tile (512 x 16B granules); LDS dest wave-uniform + lane*16 (linear both sides)
  auto stage = [&](const u16* basep, size_t granule0, u16* tile) {
    const char* src = (const char*)basep + granule0 * 16;
    char* wbase = (char*)tile + (size_t)wave * 1024;
    gl_lds16(src + (size_t)tid * 16, wbase);
    gl_lds16(src + (size_t)(tid + 256) * 16, wbase + 4096);
  };

  stage(A, ((size_t)0 * Astride + row0) * 4, &Atile[0][0]);
  stage(W, ((size_t)0 * N + col0) * 4, &Btile[0][0]);

  f32x4 acc[4][4];
#pragma unroll
  for (int n = 0; n < 4; ++n) {
    float bv = bias[col0 + wc * 64 + n * 16 + l15];
    f32x4 init = {bv, bv, bv, bv};
#pragma unroll
    for (int m = 0; m < 4; ++m) acc[m][n] = init;
  }

  int cur = 0;
  for (int kc = 0; kc < NK; ++kc) {
    __syncthreads();  // vmcnt(0)+lgkmcnt(0) drained before s_barrier (compiler-emitted)
    if (kc + 1 < NK) {
      stage(A, ((size_t)(kc + 1) * Astride + row0) * 4, &Atile[cur ^ 1][0]);
      stage(W, ((size_t)(kc + 1) * N + col0) * 4, &Btile[cur ^ 1][0]);
    }
    short8 a[4], b[4];
#pragma unroll
    for (int m = 0; m < 4; ++m)
      a[m] = *(const short8*)&Atile[cur][(wr * 64 + m * 16 + l15) * 32 + q * 8];
#pragma unroll
    for (int n = 0; n < 4; ++n)
      b[n] = *(const short8*)&Btile[cur][(wc * 64 + n * 16 + l15) * 32 + q * 8];
#pragma unroll
    for (int m = 0; m < 4; ++m)
#pragma unroll
      for (int n = 0; n < 4; ++n)
        acc[m][n] = __builtin_amdgcn_mfma_f32_16x16x32_bf16(a[m], b[n], acc[m][n], 0, 0, 0);
    cur ^= 1;
  }

  // epilogue: D row = (lane>>4)*4 + reg, col = lane&15 (m89-verified map)
#pragma unroll
  for (int m = 0; m < 4; ++m) {
#pragma unroll
    for (int r = 0; r < 4; ++r) {
      int row = row0 + wr * 64 + m * 16 + q * 4 + r;
      if (row >= mc) continue;
      int gidx = 0;
      if (GATHER) gidx = batch[row] & 63;  // mask: bad batch data -> wrong result, not fault
#pragma unroll
      for (int n = 0; n < 4; ++n) {
        int col = col0 + wc * 64 + n * 16 + l15;
        float v = acc[m][n][r];
        if (GATHER) v += sigma_h[(size_t)gidx * 512 + col];
        if (LEAKY) v = v >= 0.f ? v : NEG_SLOPE * v;
        if (OUTMODE == 0)
          ((u16*)outp)[((size_t)(col >> 5) * OutStride + row) * 32 + (col & 31)] = f2bf(v);
        else if (OUTMODE == 1)
          ((u16*)outp)[(size_t)row * N + col] = f2bf(v);
        else
          ((float*)outp)[(size_t)row * N + col] = v;
      }
    }
  }
}

// ---------------- segment sum (batch sorted; local rows, batch pre-offset) ----------------
#define SS_ROWS 512
__global__ __launch_bounds__(1024) void segsum_kernel(const u16* __restrict__ emb,
                                                      const int* __restrict__ batch,
                                                      float* __restrict__ seg,
                                                      float* __restrict__ cnt, int mc) {
  __shared__ int bsh[SS_ROWS];
  int r0 = blockIdx.x * SS_ROWS;
  int tid = threadIdx.x;          // 1024
  int c = tid & 255, sub = tid >> 8;
  int nrows = mc - r0;
  if (nrows > SS_ROWS) nrows = SS_ROWS;
  for (int i = tid; i < nrows; i += 1024) bsh[i] = batch[r0 + i] & 63;  // masked
  __syncthreads();
  int i0 = sub * 128, i1 = i0 + 128;
  if (i1 > nrows) i1 = nrows;
  if (i0 < nrows) {
    float acc = 0.f;
    int curg = bsh[i0];
    for (int i = i0; i < i1; ++i) {
      int b = bsh[i];
      if (b != curg) { atomicAdd(&seg[(size_t)curg * 256 + c], acc); acc = 0.f; curg = b; }
      acc += bf2f(emb[(size_t)(r0 + i) * 256 + c]);
    }
    atomicAdd(&seg[(size_t)curg * 256 + c], acc);
    if (c == 0) {
      float ca = 0.f;
      int cu = bsh[i0];
      for (int i = i0; i < i1; ++i) {
        int b = bsh[i];
        if (b != cu) { atomicAdd(&cnt[cu], ca); ca = 0.f; cu = b; }
        ca += 1.f;
      }
      atomicAdd(&cnt[cu], ca);
    }
  }
}

// ---------------- sigma / sigma_h (fp32, tiny: G=64) ----------------
__global__ __launch_bounds__(512) void sigma_kernel(const float* __restrict__ seg,
                                                    const float* __restrict__ cnt,
                                                    const float* __restrict__ w_ag,
                                                    const float* __restrict__ b_ag,
                                                    float* __restrict__ sigma_h) {
  __shared__ float s[256];
  int g = blockIdx.x, t = threadIdx.x;  // 512 threads
  if (t < 256) {
    float c = fmaxf(cnt[g], 1.0f);
    s[t] = seg[(size_t)g * 256 + t] / c;
  }
  __syncthreads();
  float acc = b_ag[t];
  for (int k = 0; k < 256; ++k) acc += s[k] * w_ag[(size_t)k * 512 + t];
  sigma_h[(size_t)g * 512 + t] = acc;
}

// ---------------- host ----------------
extern "C" void kernel_launch(void* const* d_in, const int* in_sizes, int n_in,
                              void* d_out, int out_size, void* d_ws, size_t ws_size,
                              hipStream_t stream) {
  const float* x = (const float*)d_in[0];
  const int* batch = (const int*)d_in[1];  // harness contract: integer -> const int*
  const int M = in_sizes[0] / 128;  // 200000
  const float* phi_b[4] = {(const float*)d_in[4], (const float*)d_in[6],
                           (const float*)d_in[8], (const float*)d_in[10]};
  const float* psi_b[4] = {(const float*)d_in[12], (const float*)d_in[14],
                           (const float*)d_in[16], (const float*)d_in[18]};
  const float* b_in = (const float*)d_in[20];
  const float* w_ag = (const float*)d_in[21];
  const float* b_ag = (const float*)d_in[22];

  // weight pack order: phi0..phi3, w_in, psi0..psi3
  const int wkin[9]  = {128, 512, 512, 512, 128, 512, 512, 512, 512};
  const int wkout[9] = {512, 512, 512, 256, 512, 512, 512, 512, 128};
  const float* wsrc[9] = {(const float*)d_in[3], (const float*)d_in[5], (const float*)d_in[7],
                          (const float*)d_in[9], (const float*)d_in[19], (const float*)d_in[11],
                          (const float*)d_in[13], (const float*)d_in[15], (const float*)d_in[17]};

  // ---- adaptive row-chunking so workspace fits ws_size (measured ws=409.6MB -> P=2) ----
  size_t wbytes = 0;
  for (int i = 0; i < 9; ++i)
    wbytes += (((size_t)wkin[i] * wkout[i] * 2) + 255) & ~(size_t)255;
  const size_t xbf_b  = (((size_t)4 * M * 32 * 2 + 16384) + 255) & ~(size_t)255;
  const size_t tail_b = 65536 + 256 + 256 + 131072 + 2048;  // seg+cnt+sigh+align slop
  size_t wsz = ws_size ? ws_size : (size_t)1 << 40;
  int McCap = 0;
  for (int P = 1; ; P *= 2) {
    int mcc = ((M + P - 1) / P + 127) / 128 * 128;
    size_t buf_b = (((size_t)16 * mcc * 32 * 2 + 16384) + 255) & ~(size_t)255;
    if (wbytes + xbf_b + 2 * buf_b + tail_b <= wsz || P >= 64) { McCap = mcc; break; }
  }

  char* ws = (char*)d_ws;
  size_t o = 0;
  auto alloc = [&](size_t bytes) {
    size_t r = o;
    o = (o + bytes + 255) & ~(size_t)255;
    return r;
  };
  u16* wdst[9];
  for (int i = 0; i < 9; ++i) wdst[i] = (u16*)(ws + alloc((size_t)wkin[i] * wkout[i] * 2));
  u16* xbf = (u16*)(ws + alloc((size_t)4 * M * 32 * 2 + 16384));
  u16* bufA = (u16*)(ws + alloc((size_t)16 * McCap * 32 * 2 + 16384));
  u16* bufB = (u16*)(ws + alloc((size_t)16 * McCap * 32 * 2 + 16384));
  float* seg = (float*)(ws + alloc((size_t)64 * 256 * 4));
  float* cnt = (float*)(ws + alloc(64 * 4));
  float* sigh = (float*)(ws + alloc((size_t)64 * 512 * 4));
  (void)n_in; (void)out_size;

  // pack all 9 weights (1 launch) + x to bf16 chunked layouts
  {
    WPack p;
    int maxb = 0;
    for (int i = 0; i < 9; ++i) {
      p.src[i] = wsrc[i]; p.dst[i] = wdst[i]; p.kout[i] = wkout[i];
      p.n4[i] = wkin[i] * wkout[i] / 4;
      int b = (p.n4[i] + 255) / 256;
      if (b > maxb) maxb = b;
    }
    hipLaunchKernelGGL(cvt_w_all_kernel, dim3(maxb, 9), dim3(256), 0, stream, p);
  }
  {
    size_t total = (size_t)4 * M * 32;
    int blocks = (int)((total / 4 + 255) / 256);
    hipLaunchKernelGGL(cvt_x_kernel, dim3(blocks), dim3(256), 0, stream, x, xbf, M);
  }

  const int* nob = nullptr;
  const float* nof = nullptr;
  const int nChunks = (M + McCap - 1) / McCap;

  // phi chain + segment-sum, per row-chunk (seg accumulates across chunks)
  hipMemsetAsync(seg, 0, (size_t)64 * 256 * 4 + 256, stream);  // seg + cnt contiguous
  for (int c = 0; c < nChunks; ++c) {
    const int cs = c * McCap;
    const int mc = (M - cs < McCap) ? (M - cs) : McCap;
    if (mc <= 0) break;
    const int RBc = (mc + 127) / 128;
    const u16* xc = xbf + (size_t)cs * 32;
    gemm_pass<true, 0, false, 4><<<RBc * 4, 256, 0, stream>>>(xc, M, wdst[0], phi_b[0], bufA, McCap, nob, nof, mc, 512, 128);
    gemm_pass<true, 0, false, 4><<<RBc * 4, 256, 0, stream>>>(bufA, McCap, wdst[1], phi_b[1], bufB, McCap, nob, nof, mc, 512, 512);
    gemm_pass<true, 0, false, 4><<<RBc * 4, 256, 0, stream>>>(bufB, McCap, wdst[2], phi_b[2], bufA, McCap, nob, nof, mc, 512, 512);
    gemm_pass<true, 1, false, 2><<<RBc * 2, 256, 0, stream>>>(bufA, McCap, wdst[3], phi_b[3], bufB, 0, nob, nof, mc, 256, 512);
    hipLaunchKernelGGL(segsum_kernel, dim3((mc + SS_ROWS - 1) / SS_ROWS), dim3(1024), 0, stream,
                       bufB, batch + cs, seg, cnt, mc);
  }

  hipLaunchKernelGGL(sigma_kernel, dim3(64), dim3(512), 0, stream, seg, cnt, w_ag, b_ag, sigh);

  // psi chain per row-chunk: psi_in = leaky(x@w_in + b_in + sigma_h[batch]); last layer f32->d_out
  for (int c = 0; c < nChunks; ++c) {
    const int cs = c * McCap;
    const int mc = (M - cs < McCap) ? (M - cs) : McCap;
    if (mc <= 0) break;
    const int RBc = (mc + 127) / 128;
    const u16* xc = xbf + (size_t)cs * 32;
    float* outc = (float*)d_out + (size_t)cs * 128;
    gemm_pass<true, 0, true, 4><<<RBc * 4, 256, 0, stream>>>(xc, M, wdst[4], b_in, bufA, McCap, batch + cs, sigh, mc, 512, 128);
    gemm_pass<true, 0, false, 4><<<RBc * 4, 256, 0, stream>>>(bufA, McCap, wdst[5], psi_b[0], bufB, McCap, nob, nof, mc, 512, 512);
    gemm_pass<true, 0, false, 4><<<RBc * 4, 256, 0, stream>>>(bufB, McCap, wdst[6], psi_b[1], bufA, McCap, nob, nof, mc, 512, 512);
    gemm_pass<true, 0, false, 4><<<RBc * 4, 256, 0, stream>>>(bufA, McCap, wdst[7], psi_b[2], bufB, McCap, nob, nof, mc, 512, 512);
    gemm_pass<false, 2, false, 1><<<RBc * 1, 256, 0, stream>>>(bufB, McCap, wdst[8], psi_b[3], outc, 0, nob, nof, mc, 128, 512);
  }
}